// Round 9
// baseline (230.150 us; speedup 1.0000x reference)
//
#include <hip/hip_runtime.h>
#include <hip/hip_bf16.h>

#define NL 8
#define HD 4096
#define RD 64
#define MD 4096
#define NGC 512  // NL*RD
#define KSPLIT 4

typedef __bf16 bf16x8 __attribute__((ext_vector_type(8)));
typedef float f32x4 __attribute__((ext_vector_type(4)));
typedef unsigned short ushort8 __attribute__((ext_vector_type(8)));
typedef float float4v __attribute__((ext_vector_type(4)));

__device__ __forceinline__ unsigned short f2bf(float f) {
    union { __hip_bfloat16 b; unsigned short u; } c;
    c.b = __float2bfloat16(f);
    return c.u;
}

__device__ __forceinline__ void gload_lds16(const void* g, void* l) {
    auto gp = (const __attribute__((address_space(1))) unsigned int*)(g);
    auto lp = (__attribute__((address_space(3))) unsigned int*)(l);
    __builtin_amdgcn_global_load_lds(gp, lp, 16, 0, 0);
}

// Fused setup: transpose-cast preps + Gram partials in one launch.
__global__ __launch_bounds__(256) void k_setup(const float* __restrict__ A,
                                               const float* __restrict__ B,
                                               unsigned short* __restrict__ At,
                                               unsigned short* __restrict__ Bt,
                                               float* __restrict__ Gp) {
    __shared__ float BUF[64 * 129];
    unsigned short* T = (unsigned short*)BUF;   // [64][65] when prepping
    int t = threadIdx.x;
    int bb = blockIdx.x;
    if (bb < 512) {
        int n = bb >> 6;
        int h0 = (bb & 63) << 6;
        const float* src = A + (size_t)n * HD * RD;
#pragma unroll
        for (int rep = 0; rep < 16; ++rep) {
            int flat = rep * 256 + t;
            int hh = flat >> 6, rr = flat & 63;
            T[hh * 65 + rr] = f2bf(src[(size_t)(h0 + hh) * RD + rr]);
        }
        __syncthreads();
#pragma unroll
        for (int rep = 0; rep < 16; ++rep) {
            int flat = rep * 256 + t;
            int rr = flat >> 6, hh = flat & 63;
            At[(size_t)(n * RD + rr) * HD + h0 + hh] = T[hh * 65 + rr];
        }
    } else if (bb < 1024) {
        int b2 = bb - 512;
        int n = b2 >> 6;
        int h0 = (b2 & 63) << 6;
        const float* src = B + (size_t)n * RD * HD;
#pragma unroll
        for (int rep = 0; rep < 16; ++rep) {
            int flat = rep * 256 + t;
            int rr = flat >> 6, hh = flat & 63;
            T[rr * 65 + hh] = f2bf(src[(size_t)rr * HD + h0 + hh]);
        }
        __syncthreads();
        unsigned short* dst = Bt + (size_t)n * HD * RD;
#pragma unroll
        for (int rep = 0; rep < 16; ++rep) {
            int flat = rep * 256 + t;
            int hh = flat >> 6, rr = flat & 63;
            dst[(size_t)(h0 + hh) * RD + rr] = T[rr * 65 + hh];
        }
    } else {
        int g = bb - 1024;                    // 0..255
        int n = g >> 5;
        int c = g & 31;
        int k0 = c << 7;
        float* Bl = BUF;                      // [64][129]
        const float* src = B + (size_t)n * RD * HD + k0;
#pragma unroll
        for (int rep = 0; rep < 8; ++rep) {
            int flat = (rep * 256 + t) * 4;
            int rr = flat >> 7, hh = flat & 127;
            float4v v = *(const float4v*)(src + (size_t)rr * HD + hh);
            Bl[rr * 129 + hh] = v[0]; Bl[rr * 129 + hh + 1] = v[1];
            Bl[rr * 129 + hh + 2] = v[2]; Bl[rr * 129 + hh + 3] = v[3];
        }
        __syncthreads();
        int i0 = (t >> 4) << 2;
        int j0 = (t & 15) << 2;
        float acc[4][4];
#pragma unroll
        for (int a = 0; a < 4; ++a)
#pragma unroll
            for (int b = 0; b < 4; ++b) acc[a][b] = 0.f;
        for (int h = 0; h < 128; ++h) {
            float bi[4], bj[4];
#pragma unroll
            for (int a = 0; a < 4; ++a) { bi[a] = Bl[(i0 + a) * 129 + h]; bj[a] = Bl[(j0 + a) * 129 + h]; }
#pragma unroll
            for (int a = 0; a < 4; ++a)
#pragma unroll
                for (int b = 0; b < 4; ++b) acc[a][b] += bi[a] * bj[b];
        }
        float* gdst = Gp + (size_t)(n * 32 + c) * RD * RD;
#pragma unroll
        for (int a = 0; a < 4; ++a)
#pragma unroll
            for (int b = 0; b < 4; ++b)
                gdst[(i0 + a) * RD + j0 + b] = acc[a][b];
    }
}

// GEMM1 (128x128 tile, operand-swapped, KSPLIT=4 -> 512 blocks = 2/CU) + gram_reduce tail.
__global__ __launch_bounds__(256) void k_gemm1(const float* __restrict__ x,
                                               const unsigned short* __restrict__ At,
                                               float* __restrict__ inter_p,
                                               const float* __restrict__ Gp,
                                               float* __restrict__ G) {
    __shared__ unsigned short As[2][128 * 64];
    __shared__ unsigned short Bs[2][128 * 64];
    int t = threadIdx.x, lane = t & 63;
    int bid = blockIdx.x;
    if (bid >= 512) {
        int idx = (bid - 512) * 256 + t;      // 0..32767
        int n = idx >> 12;
        int rem = idx & 4095;
        const float* src = Gp + (size_t)n * 32 * 4096 + rem;
        float sum = 0.f;
#pragma unroll
        for (int c = 0; c < 32; ++c) sum += src[(size_t)c * 4096];
        G[idx] = sum;
        return;
    }
    int ks = bid & 3;
    int c0 = ((bid >> 2) & 3) * 128;
    int m0 = (bid >> 4) * 128;
    int kbase = ks * 1024;

    int sa_r = t >> 3, sa_sg = t & 7;
    int sa_sw = sa_sg ^ (sa_r & 7);
    const float* xrow[4];
#pragma unroll
    for (int j = 0; j < 4; ++j)
        xrow[j] = x + (size_t)(m0 + sa_r + 32 * j) * HD + sa_sg * 8;

    int wv = t >> 6;
    int wm = (wv >> 1) * 64;
    int wc = (wv & 1) * 64;

    f32x4 acc[4][4];
#pragma unroll
    for (int cf = 0; cf < 4; ++cf)
#pragma unroll
        for (int mf = 0; mf < 4; ++mf) acc[cf][mf] = (f32x4){0.f, 0.f, 0.f, 0.f};

    {
#pragma unroll
        for (int q = 0; q < 4; ++q) {
            int flat = q * 256 + t;
            int cc = flat >> 3, sg = flat & 7;
            int sw = sg ^ (cc & 7);
            gload_lds16(At + (size_t)(c0 + cc) * HD + kbase + sw * 8,
                        (void*)&Bs[0][(q * 256 + (t & ~63)) * 8]);
        }
#pragma unroll
        for (int j = 0; j < 4; ++j) {
            float4v v0 = *(const float4v*)(xrow[j] + kbase);
            float4v v1 = *(const float4v*)(xrow[j] + kbase + 4);
            ushort8 sv;
#pragma unroll
            for (int q = 0; q < 4; ++q) { sv[q] = f2bf(v0[q]); sv[q + 4] = f2bf(v1[q]); }
            *(ushort8*)&As[0][(sa_r + 32 * j) * 64 + sa_sw * 8] = sv;
        }
    }
    __syncthreads();

    float4v pa[4][2];
    for (int kt = 0; kt < 16; ++kt) {
        int cur = kt & 1;
        int knext = kbase + (kt + 1) * 64;
        if (kt < 15) {
#pragma unroll
            for (int q = 0; q < 4; ++q) {
                int flat = q * 256 + t;
                int cc = flat >> 3, sg = flat & 7;
                int sw = sg ^ (cc & 7);
                gload_lds16(At + (size_t)(c0 + cc) * HD + knext + sw * 8,
                            (void*)&Bs[cur ^ 1][(q * 256 + (t & ~63)) * 8]);
            }
#pragma unroll
            for (int j = 0; j < 4; ++j) {
                pa[j][0] = *(const float4v*)(xrow[j] + knext);
                pa[j][1] = *(const float4v*)(xrow[j] + knext + 4);
            }
        }
        const unsigned short* as = As[cur];
        const unsigned short* bs = Bs[cur];
#pragma unroll
        for (int kk = 0; kk < 2; ++kk) {
            int seg = kk * 4 + (lane >> 4);
            bf16x8 a_c[4], b_x[4];
#pragma unroll
            for (int cf = 0; cf < 4; ++cf) {
                int row = wc + cf * 16 + (lane & 15);
                a_c[cf] = *(const bf16x8*)&bs[row * 64 + (seg ^ (row & 7)) * 8];
            }
#pragma unroll
            for (int mf = 0; mf < 4; ++mf) {
                int col = wm + mf * 16 + (lane & 15);
                b_x[mf] = *(const bf16x8*)&as[col * 64 + (seg ^ (col & 7)) * 8];
            }
#pragma unroll
            for (int cf = 0; cf < 4; ++cf)
#pragma unroll
                for (int mf = 0; mf < 4; ++mf)
                    acc[cf][mf] = __builtin_amdgcn_mfma_f32_16x16x32_bf16(
                        a_c[cf], b_x[mf], acc[cf][mf], 0, 0, 0);
        }
        if (kt < 15) {
#pragma unroll
            for (int j = 0; j < 4; ++j) {
                ushort8 sv;
#pragma unroll
                for (int q = 0; q < 4; ++q) { sv[q] = f2bf(pa[j][0][q]); sv[q + 4] = f2bf(pa[j][1][q]); }
                *(ushort8*)&As[cur ^ 1][(sa_r + 32 * j) * 64 + sa_sw * 8] = sv;
            }
        }
        __syncthreads();
    }
    float* dst = inter_p + (size_t)ks * MD * NGC;
#pragma unroll
    for (int mf = 0; mf < 4; ++mf) {
        int m = m0 + wm + mf * 16 + (lane & 15);
#pragma unroll
        for (int cf = 0; cf < 4; ++cf) {
            int c = c0 + wc + cf * 16 + (lane >> 4) * 4;
            *(float4v*)&dst[(size_t)m * NGC + c] = acc[cf][mf];
        }
    }
}

// s[n][m] = 2/(sqrt(i^T G_n i)+eps); emit summed bf16 intermediate (4 K-split partials).
__global__ __launch_bounds__(256) void k_scale(const float* __restrict__ inter_p,
                                               const float* __restrict__ G,
                                               float* __restrict__ s,
                                               unsigned short* __restrict__ interbf) {
    __shared__ float Gs[64][65];
    __shared__ float Ib[4][8][64];
    int t = threadIdx.x, lane = t & 63, wv = t >> 6;
    int n = blockIdx.x >> 7;
    int m0 = (blockIdx.x & 127) << 5;
    const float* gsrc = G + n * 4096;
#pragma unroll
    for (int rep = 0; rep < 16; ++rep) {
        int flat = rep * 256 + t;
        Gs[flat >> 6][flat & 63] = gsrc[flat];
    }
#pragma unroll
    for (int r = 0; r < 8; ++r) {
        int m = m0 + wv * 8 + r;
        size_t off = (size_t)m * NGC + n * RD + lane;
        float Iv = (inter_p[off] + inter_p[(size_t)MD * NGC + off]) +
                   (inter_p[2 * (size_t)MD * NGC + off] + inter_p[3 * (size_t)MD * NGC + off]);
        interbf[off] = f2bf(Iv);
        Ib[wv][r][lane] = Iv;
    }
    __syncthreads();
    float greg[64];
#pragma unroll
    for (int j = 0; j < 64; ++j) greg[j] = Gs[lane][j];
#pragma unroll
    for (int r = 0; r < 8; ++r) {
        const float* ib = Ib[wv][r];
        float t0 = 0.f, t1 = 0.f, t2 = 0.f, t3 = 0.f;
#pragma unroll
        for (int j = 0; j < 64; j += 4) {
            t0 += greg[j]     * ib[j];
            t1 += greg[j + 1] * ib[j + 1];
            t2 += greg[j + 2] * ib[j + 2];
            t3 += greg[j + 3] * ib[j + 3];
        }
        float pl = ((t0 + t1) + (t2 + t3)) * ib[lane];
#pragma unroll
        for (int o = 32; o; o >>= 1) pl += __shfl_xor(pl, o);
        if (lane == 0) {
            int m = m0 + wv * 8 + r;
            s[n * MD + m] = 2.0f / (sqrtf(fmaxf(pl, 0.f)) + 1e-8f);
        }
    }
}

// GEMM2: 64m x 128h tile, 3 blocks/CU (48KB LDS), n-loop inside, x in regs,
// counted-vmcnt barrier keeps stores in flight.
__global__ __launch_bounds__(256, 3) void k_gemm2(const float* __restrict__ x,
                                                  const unsigned short* __restrict__ interbf,
                                                  const unsigned short* __restrict__ Bt,
                                                  const float* __restrict__ s,
                                                  float* __restrict__ out) {
    __shared__ unsigned short As[2][64 * 64];
    __shared__ unsigned short Bs[2][128 * 64];
    int t = threadIdx.x, lane = t & 63, wv = t >> 6;
    int b = blockIdx.x;
    int xcd = b & 7;
    int idx = b >> 3;                          // 0..255
    int h0 = (xcd * 4 + (idx & 3)) * 128;      // 4 h-slabs per XCD, L2-resident Bt
    int m0 = (idx >> 2) * 64;                  // consecutive blocks share m0 -> interbf L2 reuse

    int wm = (wv >> 1) * 32;
    int wh = (wv & 1) * 64;

    // prologue: stage n=0 into buf 0 (4 Bs + 2 As gloads)
#pragma unroll
    for (int q = 0; q < 4; ++q) {
        int flat = q * 256 + t;
        int h = flat >> 3, sg = flat & 7;
        int sw = sg ^ (h & 7);
        gload_lds16(Bt + (size_t)(0 * HD + h0 + h) * RD + sw * 8,
                    (void*)&Bs[0][(q * 256 + (t & ~63)) * 8]);
    }
#pragma unroll
    for (int q = 0; q < 2; ++q) {
        int flat = q * 256 + t;
        int m = flat >> 3, sg = flat & 7;
        int sw = sg ^ (m & 7);
        gload_lds16(interbf + (size_t)(m0 + m) * NGC + 0 * RD + sw * 8,
                    (void*)&As[0][(q * 256 + (t & ~63)) * 8]);
    }
    // x tile is n-invariant: load ONCE into registers
    float4v xv[2][4];
#pragma unroll
    for (int mf = 0; mf < 2; ++mf) {
        int m = m0 + wm + mf * 16 + (lane & 15);
#pragma unroll
        for (int hf = 0; hf < 4; ++hf) {
            int h = h0 + wh + hf * 16 + (lane >> 4) * 4;
            xv[mf][hf] = *(const float4v*)&x[(size_t)m * HD + h];
        }
    }
    asm volatile("s_waitcnt vmcnt(0)" ::: "memory");
    __syncthreads();

    for (int n = 0; n < NL; ++n) {
        int cur = n & 1;
        if (n < NL - 1) {
            // prefetch n+1 (6 gload_lds, oldest VMEM ops of this iteration)
#pragma unroll
            for (int q = 0; q < 4; ++q) {
                int flat = q * 256 + t;
                int h = flat >> 3, sg = flat & 7;
                int sw = sg ^ (h & 7);
                gload_lds16(Bt + (size_t)((n + 1) * HD + h0 + h) * RD + sw * 8,
                            (void*)&Bs[cur ^ 1][(q * 256 + (t & ~63)) * 8]);
            }
#pragma unroll
            for (int q = 0; q < 2; ++q) {
                int flat = q * 256 + t;
                int m = flat >> 3, sg = flat & 7;
                int sw = sg ^ (m & 7);
                gload_lds16(interbf + (size_t)(m0 + m) * NGC + (n + 1) * RD + sw * 8,
                            (void*)&As[cur ^ 1][(q * 256 + (t & ~63)) * 8]);
            }
        }
        asm volatile("" ::: "memory");   // pin: prefetch issued before everything below

        f32x4 acc[4][2];
#pragma unroll
        for (int hf = 0; hf < 4; ++hf)
#pragma unroll
            for (int mf = 0; mf < 2; ++mf) acc[hf][mf] = (f32x4){0.f, 0.f, 0.f, 0.f};

        const unsigned short* as = As[cur];
        const unsigned short* bs = Bs[cur];
#pragma unroll
        for (int kk = 0; kk < 2; ++kk) {
            int seg = kk * 4 + (lane >> 4);
            bf16x8 a_h[4], b_m[2];
#pragma unroll
            for (int hf = 0; hf < 4; ++hf) {
                int row = wh + hf * 16 + (lane & 15);
                a_h[hf] = *(const bf16x8*)&bs[row * 64 + (seg ^ (row & 7)) * 8];
            }
#pragma unroll
            for (int mf = 0; mf < 2; ++mf) {
                int col = wm + mf * 16 + (lane & 15);
                b_m[mf] = *(const bf16x8*)&as[col * 64 + (seg ^ (col & 7)) * 8];
            }
#pragma unroll
            for (int hf = 0; hf < 4; ++hf)
#pragma unroll
                for (int mf = 0; mf < 2; ++mf)
                    acc[hf][mf] = __builtin_amdgcn_mfma_f32_16x16x32_bf16(
                        a_h[hf], b_m[mf], acc[hf][mf], 0, 0, 0);
        }

        // epilogue: 8 dwordx4 stores (x from regs), newest VMEM
        size_t obase = (size_t)n * MD * HD;
#pragma unroll
        for (int mf = 0; mf < 2; ++mf) {
            int m = m0 + wm + mf * 16 + (lane & 15);
            float sv = s[n * MD + m];
#pragma unroll
            for (int hf = 0; hf < 4; ++hf) {
                int h = h0 + wh + hf * 16 + (lane >> 4) * 4;
                float4v r;
#pragma unroll
                for (int j = 0; j < 4; ++j) r[j] = xv[mf][hf][j] + sv * acc[hf][mf][j];
                *(float4v*)&out[obase + (size_t)m * HD + h] = r;
            }
        }
        if (n < NL - 1) {
            // drain the 6 prefetch gloads (oldest); leave <=8 stores in flight
            asm volatile("s_waitcnt vmcnt(8)\n\ts_barrier" ::: "memory");
        }
    }
}

extern "C" void kernel_launch(void* const* d_in, const int* in_sizes, int n_in,
                              void* d_out, int out_size, void* d_ws, size_t ws_size,
                              hipStream_t stream) {
    const float* x = (const float*)d_in[0];
    const float* lA = (const float*)d_in[1];
    const float* lB = (const float*)d_in[2];
    float* out = (float*)d_out;
    char* ws = (char*)d_ws;
    unsigned short* At      = (unsigned short*)(ws);              //  4 MB
    unsigned short* Bt      = (unsigned short*)(ws + 4194304);    //  4 MB
    float*          inter_p = (float*)(ws + 8388608);             // 32 MB ([4][M][NGC])
    float*          Gp      = (float*)(ws + 41943040);            //  4 MB
    float*          G       = (float*)(ws + 46137344);            // 128 KB
    float*          s       = (float*)(ws + 46268416);            // 128 KB
    unsigned short* interbf = (unsigned short*)(ws + 46399488);   //  4 MB

    k_setup<<<1280, 256, 0, stream>>>(lA, lB, At, Bt, Gp);
    k_gemm1<<<640, 256, 0, stream>>>(x, At, inter_p, Gp, G);
    k_scale<<<1024, 256, 0, stream>>>(inter_p, G, s, interbf);
    k_gemm2<<<2048, 256, 0, stream>>>(x, interbf, Bt, s, out);
}

// Round 10
// 209.857 us; speedup vs baseline: 1.0967x; 1.0967x over previous
//
#include <hip/hip_runtime.h>
#include <hip/hip_bf16.h>

#define NL 8
#define HD 4096
#define RD 64
#define MD 4096
#define NGC 512  // NL*RD
#define KSPLIT 4

typedef __bf16 bf16x8 __attribute__((ext_vector_type(8)));
typedef float f32x4 __attribute__((ext_vector_type(4)));
typedef unsigned short ushort8 __attribute__((ext_vector_type(8)));
typedef unsigned short ushort4v __attribute__((ext_vector_type(4)));
typedef float float4v __attribute__((ext_vector_type(4)));

__device__ __forceinline__ unsigned short f2bf(float f) {
    union { __hip_bfloat16 b; unsigned short u; } c;
    c.b = __float2bfloat16(f);
    return c.u;
}

__device__ __forceinline__ float bf2f(unsigned short u) {
    union { unsigned int u; float f; } c;
    c.u = ((unsigned int)u) << 16;
    return c.f;
}

__device__ __forceinline__ void gload_lds16(const void* g, void* l) {
    auto gp = (const __attribute__((address_space(1))) unsigned int*)(g);
    auto lp = (__attribute__((address_space(3))) unsigned int*)(l);
    __builtin_amdgcn_global_load_lds(gp, lp, 16, 0, 0);
}

// Fused setup: transpose-cast preps + Gram partials in one launch.
__global__ __launch_bounds__(256) void k_setup(const float* __restrict__ A,
                                               const float* __restrict__ B,
                                               unsigned short* __restrict__ At,
                                               unsigned short* __restrict__ Bt,
                                               float* __restrict__ Gp) {
    __shared__ float BUF[64 * 129];
    unsigned short* T = (unsigned short*)BUF;   // [64][65] when prepping
    int t = threadIdx.x;
    int bb = blockIdx.x;
    if (bb < 512) {
        int n = bb >> 6;
        int h0 = (bb & 63) << 6;
        const float* src = A + (size_t)n * HD * RD;
#pragma unroll
        for (int rep = 0; rep < 16; ++rep) {
            int flat = rep * 256 + t;
            int hh = flat >> 6, rr = flat & 63;
            T[hh * 65 + rr] = f2bf(src[(size_t)(h0 + hh) * RD + rr]);
        }
        __syncthreads();
#pragma unroll
        for (int rep = 0; rep < 16; ++rep) {
            int flat = rep * 256 + t;
            int rr = flat >> 6, hh = flat & 63;
            At[(size_t)(n * RD + rr) * HD + h0 + hh] = T[hh * 65 + rr];
        }
    } else if (bb < 1024) {
        int b2 = bb - 512;
        int n = b2 >> 6;
        int h0 = (b2 & 63) << 6;
        const float* src = B + (size_t)n * RD * HD;
#pragma unroll
        for (int rep = 0; rep < 16; ++rep) {
            int flat = rep * 256 + t;
            int rr = flat >> 6, hh = flat & 63;
            T[rr * 65 + hh] = f2bf(src[(size_t)rr * HD + h0 + hh]);
        }
        __syncthreads();
        unsigned short* dst = Bt + (size_t)n * HD * RD;
#pragma unroll
        for (int rep = 0; rep < 16; ++rep) {
            int flat = rep * 256 + t;
            int hh = flat >> 6, rr = flat & 63;
            dst[(size_t)(h0 + hh) * RD + rr] = T[rr * 65 + hh];
        }
    } else {
        int g = bb - 1024;                    // 0..255
        int n = g >> 5;
        int c = g & 31;
        int k0 = c << 7;
        float* Bl = BUF;                      // [64][129]
        const float* src = B + (size_t)n * RD * HD + k0;
#pragma unroll
        for (int rep = 0; rep < 8; ++rep) {
            int flat = (rep * 256 + t) * 4;
            int rr = flat >> 7, hh = flat & 127;
            float4v v = *(const float4v*)(src + (size_t)rr * HD + hh);
            Bl[rr * 129 + hh] = v[0]; Bl[rr * 129 + hh + 1] = v[1];
            Bl[rr * 129 + hh + 2] = v[2]; Bl[rr * 129 + hh + 3] = v[3];
        }
        __syncthreads();
        int i0 = (t >> 4) << 2;
        int j0 = (t & 15) << 2;
        float acc[4][4];
#pragma unroll
        for (int a = 0; a < 4; ++a)
#pragma unroll
            for (int b = 0; b < 4; ++b) acc[a][b] = 0.f;
        for (int h = 0; h < 128; ++h) {
            float bi[4], bj[4];
#pragma unroll
            for (int a = 0; a < 4; ++a) { bi[a] = Bl[(i0 + a) * 129 + h]; bj[a] = Bl[(j0 + a) * 129 + h]; }
#pragma unroll
            for (int a = 0; a < 4; ++a)
#pragma unroll
                for (int b = 0; b < 4; ++b) acc[a][b] += bi[a] * bj[b];
        }
        float* gdst = Gp + (size_t)(n * 32 + c) * RD * RD;
#pragma unroll
        for (int a = 0; a < 4; ++a)
#pragma unroll
            for (int b = 0; b < 4; ++b)
                gdst[(i0 + a) * RD + j0 + b] = acc[a][b];
    }
}

// GEMM1 (128x128 tile, operand-swapped, KSPLIT=4 -> 512 blocks = 2/CU) + gram_reduce tail.
// Partials stored bf16 (halves partial traffic; k_scale sums in fp32).
__global__ __launch_bounds__(256) void k_gemm1(const float* __restrict__ x,
                                               const unsigned short* __restrict__ At,
                                               unsigned short* __restrict__ inter_pbf,
                                               const float* __restrict__ Gp,
                                               float* __restrict__ G) {
    __shared__ unsigned short As[2][128 * 64];
    __shared__ unsigned short Bs[2][128 * 64];
    int t = threadIdx.x, lane = t & 63;
    int bid = blockIdx.x;
    if (bid >= 512) {
        int idx = (bid - 512) * 256 + t;      // 0..32767
        int n = idx >> 12;
        int rem = idx & 4095;
        const float* src = Gp + (size_t)n * 32 * 4096 + rem;
        float sum = 0.f;
#pragma unroll
        for (int c = 0; c < 32; ++c) sum += src[(size_t)c * 4096];
        G[idx] = sum;
        return;
    }
    int ks = bid & 3;
    int c0 = ((bid >> 2) & 3) * 128;
    int m0 = (bid >> 4) * 128;
    int kbase = ks * 1024;

    int sa_r = t >> 3, sa_sg = t & 7;
    int sa_sw = sa_sg ^ (sa_r & 7);
    const float* xrow[4];
#pragma unroll
    for (int j = 0; j < 4; ++j)
        xrow[j] = x + (size_t)(m0 + sa_r + 32 * j) * HD + sa_sg * 8;

    int wv = t >> 6;
    int wm = (wv >> 1) * 64;
    int wc = (wv & 1) * 64;

    f32x4 acc[4][4];
#pragma unroll
    for (int cf = 0; cf < 4; ++cf)
#pragma unroll
        for (int mf = 0; mf < 4; ++mf) acc[cf][mf] = (f32x4){0.f, 0.f, 0.f, 0.f};

    {
#pragma unroll
        for (int q = 0; q < 4; ++q) {
            int flat = q * 256 + t;
            int cc = flat >> 3, sg = flat & 7;
            int sw = sg ^ (cc & 7);
            gload_lds16(At + (size_t)(c0 + cc) * HD + kbase + sw * 8,
                        (void*)&Bs[0][(q * 256 + (t & ~63)) * 8]);
        }
#pragma unroll
        for (int j = 0; j < 4; ++j) {
            float4v v0 = *(const float4v*)(xrow[j] + kbase);
            float4v v1 = *(const float4v*)(xrow[j] + kbase + 4);
            ushort8 sv;
#pragma unroll
            for (int q = 0; q < 4; ++q) { sv[q] = f2bf(v0[q]); sv[q + 4] = f2bf(v1[q]); }
            *(ushort8*)&As[0][(sa_r + 32 * j) * 64 + sa_sw * 8] = sv;
        }
    }
    __syncthreads();

    float4v pa[4][2];
    for (int kt = 0; kt < 16; ++kt) {
        int cur = kt & 1;
        int knext = kbase + (kt + 1) * 64;
        if (kt < 15) {
#pragma unroll
            for (int q = 0; q < 4; ++q) {
                int flat = q * 256 + t;
                int cc = flat >> 3, sg = flat & 7;
                int sw = sg ^ (cc & 7);
                gload_lds16(At + (size_t)(c0 + cc) * HD + knext + sw * 8,
                            (void*)&Bs[cur ^ 1][(q * 256 + (t & ~63)) * 8]);
            }
#pragma unroll
            for (int j = 0; j < 4; ++j) {
                pa[j][0] = *(const float4v*)(xrow[j] + knext);
                pa[j][1] = *(const float4v*)(xrow[j] + knext + 4);
            }
        }
        const unsigned short* as = As[cur];
        const unsigned short* bs = Bs[cur];
#pragma unroll
        for (int kk = 0; kk < 2; ++kk) {
            int seg = kk * 4 + (lane >> 4);
            bf16x8 a_c[4], b_x[4];
#pragma unroll
            for (int cf = 0; cf < 4; ++cf) {
                int row = wc + cf * 16 + (lane & 15);
                a_c[cf] = *(const bf16x8*)&bs[row * 64 + (seg ^ (row & 7)) * 8];
            }
#pragma unroll
            for (int mf = 0; mf < 4; ++mf) {
                int col = wm + mf * 16 + (lane & 15);
                b_x[mf] = *(const bf16x8*)&as[col * 64 + (seg ^ (col & 7)) * 8];
            }
#pragma unroll
            for (int cf = 0; cf < 4; ++cf)
#pragma unroll
                for (int mf = 0; mf < 4; ++mf)
                    acc[cf][mf] = __builtin_amdgcn_mfma_f32_16x16x32_bf16(
                        a_c[cf], b_x[mf], acc[cf][mf], 0, 0, 0);
        }
        if (kt < 15) {
#pragma unroll
            for (int j = 0; j < 4; ++j) {
                ushort8 sv;
#pragma unroll
                for (int q = 0; q < 4; ++q) { sv[q] = f2bf(pa[j][0][q]); sv[q + 4] = f2bf(pa[j][1][q]); }
                *(ushort8*)&As[cur ^ 1][(sa_r + 32 * j) * 64 + sa_sw * 8] = sv;
            }
        }
        __syncthreads();
    }
    unsigned short* dst = inter_pbf + (size_t)ks * MD * NGC;
#pragma unroll
    for (int mf = 0; mf < 4; ++mf) {
        int m = m0 + wm + mf * 16 + (lane & 15);
#pragma unroll
        for (int cf = 0; cf < 4; ++cf) {
            int c = c0 + wc + cf * 16 + (lane >> 4) * 4;
            ushort4v sv;
#pragma unroll
            for (int j = 0; j < 4; ++j) sv[j] = f2bf(acc[cf][mf][j]);
            *(ushort4v*)&dst[(size_t)m * NGC + c] = sv;
        }
    }
}

// s[n][m] = 2/(sqrt(i^T G_n i)+eps); sum 4 bf16 partials in fp32, emit summed bf16.
__global__ __launch_bounds__(256) void k_scale(const unsigned short* __restrict__ inter_pbf,
                                               const float* __restrict__ G,
                                               float* __restrict__ s,
                                               unsigned short* __restrict__ interbf) {
    __shared__ float Gs[64][65];
    __shared__ float Ib[4][8][64];
    int t = threadIdx.x, lane = t & 63, wv = t >> 6;
    int n = blockIdx.x >> 7;
    int m0 = (blockIdx.x & 127) << 5;
    const float* gsrc = G + n * 4096;
#pragma unroll
    for (int rep = 0; rep < 16; ++rep) {
        int flat = rep * 256 + t;
        Gs[flat >> 6][flat & 63] = gsrc[flat];
    }
#pragma unroll
    for (int r = 0; r < 8; ++r) {
        int m = m0 + wv * 8 + r;
        size_t off = (size_t)m * NGC + n * RD + lane;
        float Iv = (bf2f(inter_pbf[off]) + bf2f(inter_pbf[(size_t)MD * NGC + off])) +
                   (bf2f(inter_pbf[2 * (size_t)MD * NGC + off]) +
                    bf2f(inter_pbf[3 * (size_t)MD * NGC + off]));
        interbf[off] = f2bf(Iv);
        Ib[wv][r][lane] = Iv;
    }
    __syncthreads();
    float greg[64];
#pragma unroll
    for (int j = 0; j < 64; ++j) greg[j] = Gs[lane][j];
#pragma unroll
    for (int r = 0; r < 8; ++r) {
        const float* ib = Ib[wv][r];
        float t0 = 0.f, t1 = 0.f, t2 = 0.f, t3 = 0.f;
#pragma unroll
        for (int j = 0; j < 64; j += 4) {
            t0 += greg[j]     * ib[j];
            t1 += greg[j + 1] * ib[j + 1];
            t2 += greg[j + 2] * ib[j + 2];
            t3 += greg[j + 3] * ib[j + 3];
        }
        float pl = ((t0 + t1) + (t2 + t3)) * ib[lane];
#pragma unroll
        for (int o = 32; o; o >>= 1) pl += __shfl_xor(pl, o);
        if (lane == 0) {
            int m = m0 + wv * 8 + r;
            s[n * MD + m] = 2.0f / (sqrtf(fmaxf(pl, 0.f)) + 1e-8f);
        }
    }
}

// GEMM2 (R8 config: 64m x 256h, 2 blocks/CU, n-loop inside): x tile in registers
// (loaded ONCE), counted-vmcnt barrier leaves the 16 stores in flight.
__global__ __launch_bounds__(256, 2) void k_gemm2(const float* __restrict__ x,
                                                  const unsigned short* __restrict__ interbf,
                                                  const unsigned short* __restrict__ Bt,
                                                  const float* __restrict__ s,
                                                  float* __restrict__ out) {
    __shared__ unsigned short As[2][64 * 64];
    __shared__ unsigned short Bs[2][256 * 64];
    int t = threadIdx.x, lane = t & 63, wv = t >> 6;
    int b = blockIdx.x;
    int xcd = b & 7;
    int idx = b >> 3;                       // 0..127
    int h0 = (xcd * 2 + (idx >> 6)) * 256;  // 2 h-slabs per XCD
    int m0 = (idx & 63) * 64;

    int wm = (wv >> 1) * 32;
    int wh = (wv & 1) * 128;

    // prologue: stage n=0 into buf 0
#pragma unroll
    for (int q = 0; q < 8; ++q) {
        int flat = q * 256 + t;
        int h = flat >> 3, sg = flat & 7;
        int sw = sg ^ (h & 7);
        gload_lds16(Bt + (size_t)(0 * HD + h0 + h) * RD + sw * 8,
                    (void*)&Bs[0][(q * 256 + (t & ~63)) * 8]);
    }
#pragma unroll
    for (int q = 0; q < 2; ++q) {
        int flat = q * 256 + t;
        int m = flat >> 3, sg = flat & 7;
        int sw = sg ^ (m & 7);
        gload_lds16(interbf + (size_t)(m0 + m) * NGC + 0 * RD + sw * 8,
                    (void*)&As[0][(q * 256 + (t & ~63)) * 8]);
    }
    // x tile is n-invariant: load ONCE into registers
    float4v xv[2][8];
#pragma unroll
    for (int mf = 0; mf < 2; ++mf) {
        int m = m0 + wm + mf * 16 + (lane & 15);
#pragma unroll
        for (int hf = 0; hf < 8; ++hf) {
            int h = h0 + wh + hf * 16 + (lane >> 4) * 4;
            xv[mf][hf] = *(const float4v*)&x[(size_t)m * HD + h];
        }
    }
    asm volatile("s_waitcnt vmcnt(0)" ::: "memory");
    __syncthreads();

    for (int n = 0; n < NL; ++n) {
        int cur = n & 1;
        if (n < NL - 1) {
            // prefetch n+1 (10 gload_lds, oldest VMEM ops of this iteration)
#pragma unroll
            for (int q = 0; q < 8; ++q) {
                int flat = q * 256 + t;
                int h = flat >> 3, sg = flat & 7;
                int sw = sg ^ (h & 7);
                gload_lds16(Bt + (size_t)((n + 1) * HD + h0 + h) * RD + sw * 8,
                            (void*)&Bs[cur ^ 1][(q * 256 + (t & ~63)) * 8]);
            }
#pragma unroll
            for (int q = 0; q < 2; ++q) {
                int flat = q * 256 + t;
                int m = flat >> 3, sg = flat & 7;
                int sw = sg ^ (m & 7);
                gload_lds16(interbf + (size_t)(m0 + m) * NGC + (n + 1) * RD + sw * 8,
                            (void*)&As[cur ^ 1][(q * 256 + (t & ~63)) * 8]);
            }
        }
        asm volatile("" ::: "memory");   // pin: prefetch issued before everything below

        f32x4 acc[8][2];
#pragma unroll
        for (int hf = 0; hf < 8; ++hf)
#pragma unroll
            for (int mf = 0; mf < 2; ++mf) acc[hf][mf] = (f32x4){0.f, 0.f, 0.f, 0.f};

        const unsigned short* as = As[cur];
        const unsigned short* bs = Bs[cur];
#pragma unroll
        for (int kk = 0; kk < 2; ++kk) {
            int seg = kk * 4 + (lane >> 4);
            bf16x8 a_h[8], b_m[2];
#pragma unroll
            for (int hf = 0; hf < 8; ++hf) {
                int row = wh + hf * 16 + (lane & 15);
                a_h[hf] = *(const bf16x8*)&bs[row * 64 + (seg ^ (row & 7)) * 8];
            }
#pragma unroll
            for (int mf = 0; mf < 2; ++mf) {
                int col = wm + mf * 16 + (lane & 15);
                b_m[mf] = *(const bf16x8*)&as[col * 64 + (seg ^ (col & 7)) * 8];
            }
#pragma unroll
            for (int hf = 0; hf < 8; ++hf)
#pragma unroll
                for (int mf = 0; mf < 2; ++mf)
                    acc[hf][mf] = __builtin_amdgcn_mfma_f32_16x16x32_bf16(
                        a_h[hf], b_m[mf], acc[hf][mf], 0, 0, 0);
        }

        // epilogue: pure stores (x from regs) -> 16 dwordx4 stores, newest VMEM
        size_t obase = (size_t)n * MD * HD;
#pragma unroll
        for (int mf = 0; mf < 2; ++mf) {
            int m = m0 + wm + mf * 16 + (lane & 15);
            float sv = s[n * MD + m];
#pragma unroll
            for (int hf = 0; hf < 8; ++hf) {
                int h = h0 + wh + hf * 16 + (lane >> 4) * 4;
                float4v r;
#pragma unroll
                for (int j = 0; j < 4; ++j) r[j] = xv[mf][hf][j] + sv * acc[hf][mf][j];
                *(float4v*)&out[obase + (size_t)m * HD + h] = r;
            }
        }
        if (n < NL - 1) {
            // drain the 10 prefetch gloads (oldest); leave <=16 stores in flight
            asm volatile("s_waitcnt vmcnt(16)\n\ts_barrier" ::: "memory");
        }
    }
}

extern "C" void kernel_launch(void* const* d_in, const int* in_sizes, int n_in,
                              void* d_out, int out_size, void* d_ws, size_t ws_size,
                              hipStream_t stream) {
    const float* x = (const float*)d_in[0];
    const float* lA = (const float*)d_in[1];
    const float* lB = (const float*)d_in[2];
    float* out = (float*)d_out;
    char* ws = (char*)d_ws;
    unsigned short* At        = (unsigned short*)(ws);              //  4 MB
    unsigned short* Bt        = (unsigned short*)(ws + 4194304);    //  4 MB
    unsigned short* inter_pbf = (unsigned short*)(ws + 8388608);    // 16 MB ([4][M][NGC] bf16)
    float*          Gp        = (float*)(ws + 25165824);            //  4 MB
    float*          G         = (float*)(ws + 29360128);            // 128 KB
    float*          s         = (float*)(ws + 29491200);            // 128 KB
    unsigned short* interbf   = (unsigned short*)(ws + 29622272);   //  4 MB

    k_setup<<<1280, 256, 0, stream>>>(lA, lB, At, Bt, Gp);
    k_gemm1<<<640, 256, 0, stream>>>(x, At, inter_pbf, Gp, G);
    k_scale<<<1024, 256, 0, stream>>>(inter_pbf, G, s, interbf);
    k_gemm2<<<1024, 256, 0, stream>>>(x, interbf, Bt, s, out);
}